// Round 10
// baseline (200.722 us; speedup 1.0000x reference)
//
#include <hip/hip_runtime.h>
#include <hip/hip_fp16.h>
#include <cmath>

// SVC_63737314673237 round 12: X operand off the DS pipe.
// R11 post-mortem: tile bracketing complete -- 128sv x 64n @3 blocks/CU is
// the structure optimum (R6 110us / R10 101us / R11 127us). R10 profile:
// DS pipe 51% = top consumer (12 b128 reads + 6 DMA writes per wave-phase).
// R12: X B-frags are 16B-contiguous per lane -> load them straight from
// global into double-buffered registers (pBE/pBO, prefetched 1 phase ahead,
// vmcnt(8) = 4 SV-DMA + 4 frag loads in flight). Xs LDS deleted: DS reads
// 12->8, DMA writes 6->4, LDS 48->32KB. X re-reads (4x/block) are L2-hits
// (16MB split-X fits aggregate L2). Loop unrolled 2 phases/iter so the reg
// buffers are statically named (no scratch). All else verbatim R10:
// (row>>1)&3 hash, counted-vmcnt top-barrier schedule, PV-MFMA epilogue,
// [90][N] T, fused prep.

#define GAMMA 0.01f
constexpr int N  = 8192;
constexpr int D  = 256;
constexpr int S  = 5000;
constexpr int C  = 10;
constexpr int NV = 500;
constexpr int R  = 9;     // C-1
constexpr int SPAD = 5120; // 10 classes x 512 padded cols

constexpr int ROW_BLOCKS = (N + S) / 4;       // 3298 (13192 row-waves, 4/block)
constexpr int A_BLOCKS   = (16 * SPAD) / 256; // 320

typedef _Float16 f16x8 __attribute__((ext_vector_type(8)));
typedef _Float16 f16x4 __attribute__((ext_vector_type(4)));
typedef float    f32x4 __attribute__((ext_vector_type(4)));

__device__ __forceinline__ void gload16(const void* g, void* l) {
    __builtin_amdgcn_global_load_lds(
        (const __attribute__((address_space(1))) void*)g,
        (__attribute__((address_space(3))) void*)l, 16, 0, 0);
}

// ---------------- fused split + norms + a-split + svnp ----------------------
__global__ __launch_bounds__(256) void prep_kernel(const float* __restrict__ x,
                                                   const float* __restrict__ sv,
                                                   const float* __restrict__ a,
                                                   _Float16* __restrict__ xh,
                                                   _Float16* __restrict__ xl,
                                                   _Float16* __restrict__ sh,
                                                   _Float16* __restrict__ sl,
                                                   float* __restrict__ xn,
                                                   _Float16* __restrict__ ah,
                                                   _Float16* __restrict__ al,
                                                   float* __restrict__ svnp) {
    if (blockIdx.x >= ROW_BLOCKS) {
        int idx = (blockIdx.x - ROW_BLOCKS) * 256 + threadIdx.x;
        int r = idx / SPAD, col = idx - r * SPAD;
        int cls = col >> 9, j = col & 511;
        int s = cls * NV + ((j < NV) ? j : NV - 1);
        float av = (r < R && j < NV) ? a[(size_t)r * S + s] : 0.0f;
        _Float16 h = (_Float16)av;
        ah[idx] = h;
        al[idx] = (_Float16)((av - (float)h) * 4096.0f);
        return;
    }
    int gid  = blockIdx.x * blockDim.x + threadIdx.x;
    int wid  = gid >> 6;
    int lane = gid & 63;
    bool isx = wid < N;
    int  r   = isx ? wid : wid - N;
    const float* row = isx ? (x + (size_t)r * D) : (sv + (size_t)r * D);
    float4 v = reinterpret_cast<const float4*>(row)[lane];
    float s = v.x * v.x + v.y * v.y + v.z * v.z + v.w * v.w;
#pragma unroll
    for (int off = 32; off > 0; off >>= 1) s += __shfl_xor(s, off, 64);
    float vv[4] = {v.x, v.y, v.z, v.w};
    f16x4 h, l;
#pragma unroll
    for (int k = 0; k < 4; ++k) {
        _Float16 hi = (_Float16)vv[k];
        h[k] = hi;
        l[k] = (_Float16)((vv[k] - (float)hi) * 4096.0f);
    }
    size_t o = (size_t)r * D + lane * 4;
    *(f16x4*)((isx ? xh : sh) + o) = h;
    *(f16x4*)((isx ? xl : sl) + o) = l;
    if (lane == 0) {
        if (isx) {
            xn[r] = s;
        } else {
            int cls = r / NV, j = r - cls * NV;
            svnp[cls * 512 + j] = s;
            if (j == NV - 1)                      // fill pad cols 500..511
                for (int p = NV; p < 512; ++p) svnp[cls * 512 + p] = s;
        }
    }
}

// ---------------- swapped split-MFMA GEMM + exp + PV-MFMA reduce ------------
// grid: (128 row tiles, 10 classes). block 256 = 4 waves (wm,wn 2x2).
// wave tile: 64 sv x 32 n = 4x2 mfma tiles (16x16x32). 32 phases =
// 4 sv-chunks x 8 kb; SV via gload_lds double-buffer (32KB), X via
// double-buffered REGISTER fragments loaded direct from global.
// Phase: {issue SV-stage(ph+1) + X-frag(ph+1); vmcnt(8); s_barrier;
// ds_read Am; setprio MFMAs; [epilogue]; lgkmcnt(0); s_barrier}.
__global__ __launch_bounds__(256, 3) void svc_gemm(const _Float16* __restrict__ xh,
                                                   const _Float16* __restrict__ xl,
                                                   const _Float16* __restrict__ sh,
                                                   const _Float16* __restrict__ sl,
                                                   const _Float16* __restrict__ ahp,
                                                   const _Float16* __restrict__ alp,
                                                   const float* __restrict__ xnorm,
                                                   const float* __restrict__ svnp,
                                                   float* __restrict__ T) {
    __shared__ _Float16 SVs[2][2][128 * 32];  // 32KB: M-operand (sv rows)

    const int tid  = threadIdx.x;
    const int n0   = blockIdx.x * 64;
    const int cls  = blockIdx.y;
    const int w    = tid >> 6;
    const int lane = tid & 63;
    const int wm   = w >> 1;   // splits 128 m
    const int wn   = w & 1;    // splits 64 n
    const int lx   = lane & 15;
    const int quad = lane >> 4;

    float xnr[2];
#pragma unroll
    for (int nt = 0; nt < 2; ++nt)
        xnr[nt] = xnorm[n0 + wn * 32 + nt * 16 + lx];

    // Am fragment read offsets, inverse of staged K-slot perm (row>>1)&3
    int svoff[4];
#pragma unroll
    for (int mt = 0; mt < 4; ++mt) {
        int row = wm * 64 + mt * 16 + lx;
        svoff[mt] = row * 32 + ((quad - (row >> 1)) & 3) * 8;
    }

    const int arow = tid >> 2, ag = tid & 3;
    const int sg   = (ag + (arow >> 1)) & 3;
    const int segend = cls * NV + NV - 1;
    const int ldsw = w * 512;

    auto stage = [&](int ph, int buf) {
        const int ch = ph >> 3, kb = ph & 7;
        const size_t koff = (size_t)(kb * 32 + sg * 8);
        const int svbase = cls * NV + ch * 128;
        int svr0 = svbase + arow;      if (svr0 > segend) svr0 = segend;
        int svr1 = svbase + arow + 64; if (svr1 > segend) svr1 = segend;
        const size_t go0 = (size_t)svr0 * D + koff;
        const size_t go1 = (size_t)svr1 * D + koff;
        gload16(sh + go0, &SVs[buf][0][ldsw]);
        gload16(sl + go0, &SVs[buf][1][ldsw]);
        gload16(sh + go1, &SVs[buf][0][2048 + ldsw]);
        gload16(sl + go1, &SVs[buf][1][2048 + ldsw]);
    };

    // direct-from-global X fragment loads: lane holds x[row][kb*32+quad*8..+8)
    const size_t xrow0 = (size_t)(n0 + wn * 32 + lx) * D + quad * 8;
    const size_t xrow1 = (size_t)(n0 + wn * 32 + 16 + lx) * D + quad * 8;
    f16x8 pBE[2][2], pBO[2][2];        // [plane][nt], double-buffered
    auto loadB = [&](f16x8 (&dst)[2][2], int kb) {
        const size_t o0 = xrow0 + kb * 32;
        const size_t o1 = xrow1 + kb * 32;
        dst[0][0] = *(const f16x8*)(xh + o0);
        dst[1][0] = *(const f16x8*)(xl + o0);
        dst[0][1] = *(const f16x8*)(xh + o1);
        dst[1][1] = *(const f16x8*)(xl + o1);
    };

    f32x4 accM[4][2], accC[4][2];      // first-GEMM tiles [mt][nt]
#pragma unroll
    for (int mt = 0; mt < 4; ++mt)
#pragma unroll
        for (int nt = 0; nt < 2; ++nt) {
            accM[mt][nt] = (f32x4){0.f, 0.f, 0.f, 0.f};
            accC[mt][nt] = (f32x4){0.f, 0.f, 0.f, 0.f};
        }
    f32x4 accO[2], accOC[2];           // PV output tiles [nt] (r x n)
#pragma unroll
    for (int nt = 0; nt < 2; ++nt) {
        accO[nt]  = (f32x4){0.f, 0.f, 0.f, 0.f};
        accOC[nt] = (f32x4){0.f, 0.f, 0.f, 0.f};
    }

    auto compute = [&](int buf, const f16x8 (&pB)[2][2]) {
        f16x8 Am[2][4];
#pragma unroll
        for (int mt = 0; mt < 4; ++mt) {
            Am[0][mt] = *(const f16x8*)(&SVs[buf][0][svoff[mt]]);
            Am[1][mt] = *(const f16x8*)(&SVs[buf][1][svoff[mt]]);
        }
        __builtin_amdgcn_s_setprio(1);
#pragma unroll
        for (int mt = 0; mt < 4; ++mt)
#pragma unroll
            for (int nt = 0; nt < 2; ++nt) {
                accM[mt][nt] = __builtin_amdgcn_mfma_f32_16x16x32_f16(
                    Am[0][mt], pB[0][nt], accM[mt][nt], 0, 0, 0);
                accC[mt][nt] = __builtin_amdgcn_mfma_f32_16x16x32_f16(
                    Am[0][mt], pB[1][nt], accC[mt][nt], 0, 0, 0);
                accC[mt][nt] = __builtin_amdgcn_mfma_f32_16x16x32_f16(
                    Am[1][mt], pB[0][nt], accC[mt][nt], 0, 0, 0);
            }
        __builtin_amdgcn_s_setprio(0);
    };

    auto epilogue = [&](int ch) {       // exp + PV-MFMA reduce (no DS)
        const int mbase = cls * 512 + ch * 128 + wm * 64;
#pragma unroll
        for (int mt = 0; mt < 4; ++mt) {
            const size_t ao = (size_t)lx * SPAD + mbase + mt * 16 + quad * 4;
            f16x4 afh = *(const f16x4*)(ahp + ao);   // A-frag: a[r=lx, k]
            f16x4 afl = *(const f16x4*)(alp + ao);
            float4 sn4 = *(const float4*)(svnp + mbase + mt * 16 + quad * 4);
#pragma unroll
            for (int nt = 0; nt < 2; ++nt) {
                f16x4 bh, bl;   // B-frag: kv[k = quad*4+reg, col = lx]
#pragma unroll
                for (int reg = 0; reg < 4; ++reg) {
                    float dot = accM[mt][nt][reg]
                              + accC[mt][nt][reg] * (1.0f / 4096.0f);
                    float e  = fmaf(2.0f * GAMMA, dot,
                                    -GAMMA * (xnr[nt] + sn4[reg]));
                    float kv = __expf(e);
                    _Float16 h = (_Float16)kv;
                    bh[reg] = h;
                    bl[reg] = (_Float16)((kv - (float)h) * 4096.0f);
                }
                accO[nt]  = __builtin_amdgcn_mfma_f32_16x16x16f16(
                    afh, bh, accO[nt], 0, 0, 0);
                accOC[nt] = __builtin_amdgcn_mfma_f32_16x16x16f16(
                    afh, bl, accOC[nt], 0, 0, 0);
                accOC[nt] = __builtin_amdgcn_mfma_f32_16x16x16f16(
                    afl, bh, accOC[nt], 0, 0, 0);
                accM[mt][nt] = (f32x4){0.f, 0.f, 0.f, 0.f};
                accC[mt][nt] = (f32x4){0.f, 0.f, 0.f, 0.f};
            }
        }
    };

    stage(0, 0);
    loadB(pBE, 0);

    for (int it = 0; it < 16; ++it) {
        const int ph = it * 2;
        // ---- even phase (buf 0, frags pBE) ----
        stage(ph + 1, 1);
        loadB(pBO, (ph + 1) & 7);
        asm volatile("s_waitcnt vmcnt(8)" ::: "memory");
        __builtin_amdgcn_s_barrier();
        asm volatile("" ::: "memory");
        compute(0, pBE);
        asm volatile("s_waitcnt lgkmcnt(0)" ::: "memory");
        __builtin_amdgcn_s_barrier();
        asm volatile("" ::: "memory");
        // ---- odd phase (buf 1, frags pBO) ----
        if (it < 15) {
            stage(ph + 2, 0);
            loadB(pBE, (ph + 2) & 7);
            asm volatile("s_waitcnt vmcnt(8)" ::: "memory");
        } else {
            asm volatile("s_waitcnt vmcnt(0)" ::: "memory");
        }
        __builtin_amdgcn_s_barrier();
        asm volatile("" ::: "memory");
        compute(1, pBO);
        if ((it & 3) == 3) epilogue(it >> 2);   // ph+1 == 7 mod 8
        asm volatile("s_waitcnt lgkmcnt(0)" ::: "memory");
        __builtin_amdgcn_s_barrier();
        asm volatile("" ::: "memory");
    }

    // cross-wm reduce via 8KB of reused SVs space, then store T ([90][N]).
    float* scr = (float*)&SVs[0][0][0];
    if (wm == 0) {
#pragma unroll
        for (int nt = 0; nt < 2; ++nt)
#pragma unroll
            for (int reg = 0; reg < 4; ++reg) {
                int base = ((wn * 2 + nt) * 2) * 256 + (quad * 4 + reg) * 16 + lx;
                scr[base]       = accO[nt][reg];
                scr[base + 256] = accOC[nt][reg];
            }
    }
    __syncthreads();
    if (wm == 1) {
#pragma unroll
        for (int nt = 0; nt < 2; ++nt)
#pragma unroll
            for (int reg = 0; reg < 4; ++reg) {
                int r = quad * 4 + reg;
                if (r < R) {
                    int base = ((wn * 2 + nt) * 2) * 256 + r * 16 + lx;
                    float o  = accO[nt][reg]  + scr[base];
                    float oc = accOC[nt][reg] + scr[base + 256];
                    int n = n0 + wn * 32 + nt * 16 + lx;
                    T[(size_t)(r * 10 + cls) * N + n] = o + oc * (1.0f / 4096.0f);
                }
            }
    }
}

// ---------------- pairwise voting + argmax ----------------------------------
// T is [90][N]: every load below is a coalesced 1KB/wave read.
__global__ __launch_bounds__(256) void vote_kernel(const float* __restrict__ T,
                                                   const float* __restrict__ b,
                                                   int* __restrict__ out) {
    int n = blockIdx.x * blockDim.x + threadIdx.x;
    if (n >= N) return;
    float tv[90];
#pragma unroll
    for (int i = 0; i < 90; ++i) tv[i] = T[(size_t)i * N + n];
    int counts[C];
#pragma unroll
    for (int k = 0; k < C; ++k) counts[k] = 0;
    int p = 0;
#pragma unroll
    for (int i = 0; i < C; ++i) {
#pragma unroll
        for (int j = i + 1; j < C; ++j) {
            float c = tv[i * 10 + j] + tv[(j - 1) * 10 + i] + b[p];
            if (c > 0.f) counts[i]++; else counts[j]++;
            ++p;
        }
    }
    int best = 0;
#pragma unroll
    for (int k = 1; k < C; ++k)
        if (counts[k] > counts[best]) best = k;
    out[n]     = best;
    out[N + n] = best;
}

extern "C" void kernel_launch(void* const* d_in, const int* in_sizes, int n_in,
                              void* d_out, int out_size, void* d_ws, size_t ws_size,
                              hipStream_t stream) {
    const float* x  = (const float*)d_in[0];   // [8192,256]
    const float* sv = (const float*)d_in[1];   // [5000,256]
    const float* a  = (const float*)d_in[2];   // [9,5000]
    const float* b  = (const float*)d_in[3];   // [45]
    int* out = (int*)d_out;

    char* wp = (char*)d_ws;
    _Float16* xh = (_Float16*)wp;  wp += (size_t)N * D * 2;
    _Float16* xl = (_Float16*)wp;  wp += (size_t)N * D * 2;
    _Float16* sh = (_Float16*)wp;  wp += (size_t)S * D * 2;
    _Float16* sl = (_Float16*)wp;  wp += (size_t)S * D * 2;
    float* xnorm  = (float*)wp;    wp += (size_t)N * 4;
    _Float16* ahp = (_Float16*)wp; wp += (size_t)16 * SPAD * 2;
    _Float16* alp = (_Float16*)wp; wp += (size_t)16 * SPAD * 2;
    float* svnp   = (float*)wp;    wp += (size_t)SPAD * 4;
    float* T      = (float*)wp;    // [90][N]

    {   // fused split + norms + a-split + svnp (one launch)
        prep_kernel<<<ROW_BLOCKS + A_BLOCKS, 256, 0, stream>>>(
            x, sv, a, xh, xl, sh, sl, xnorm, ahp, alp, svnp);
    }
    {   // swapped GEMM + PV-MFMA reduce
        dim3 grid(N / 64, C);
        svc_gemm<<<grid, 256, 0, stream>>>(xh, xl, sh, sl, ahp, alp,
                                           xnorm, svnp, T);
    }
    {   // voting
        vote_kernel<<<N / 256, 256, 0, stream>>>(T, b, out);
    }
}

// Round 11
// 173.531 us; speedup vs baseline: 1.1567x; 1.1567x over previous
//
#include <hip/hip_runtime.h>
#include <hip/hip_fp16.h>
#include <cmath>

// SVC_63737314673237 round 13: revert R12 (uncoalesced X gather, lane
// stride 512B -> VMEM bloat, 140us) back to R10 base + ONE fix:
// chunk-top epilogue-constant prefetch.
// Diagnosed mechanism: R10's epilogue issued 12 global loads (ahp/alp/svnp)
// AFTER stage(ph+1); in-order VMEM retirement means the compiler's vmcnt
// wait before the PV-MFMA (consuming those newest loads) forces ALL older
// outstanding loads -- the whole stage(ph+1) prefetch -- to drain. Every
// chunk boundary (4x/block) silently reverted counted-vmcnt to vmcnt(0).
// Fix: load the chunk's epilogue constants into registers at chunk TOP
// ((ph&7)==0, after the top barrier): they are then OLDER than all later
// stages; consumption at ph==7 waits on nothing live. +32 VGPR, static
// indexing, no scratch. All else byte-identical to R10 (verified best:
// (row>>1)&3 conflict-free hash, counted vmcnt(6) top-barrier schedule,
// PV-MFMA epilogue, [90][N] T, fused prep).

#define GAMMA 0.01f
constexpr int N  = 8192;
constexpr int D  = 256;
constexpr int S  = 5000;
constexpr int C  = 10;
constexpr int NV = 500;
constexpr int R  = 9;     // C-1
constexpr int SPAD = 5120; // 10 classes x 512 padded cols

constexpr int ROW_BLOCKS = (N + S) / 4;       // 3298 (13192 row-waves, 4/block)
constexpr int A_BLOCKS   = (16 * SPAD) / 256; // 320

typedef _Float16 f16x8 __attribute__((ext_vector_type(8)));
typedef _Float16 f16x4 __attribute__((ext_vector_type(4)));
typedef float    f32x4 __attribute__((ext_vector_type(4)));

__device__ __forceinline__ void gload16(const void* g, void* l) {
    __builtin_amdgcn_global_load_lds(
        (const __attribute__((address_space(1))) void*)g,
        (__attribute__((address_space(3))) void*)l, 16, 0, 0);
}

// ---------------- fused split + norms + a-split + svnp ----------------------
__global__ __launch_bounds__(256) void prep_kernel(const float* __restrict__ x,
                                                   const float* __restrict__ sv,
                                                   const float* __restrict__ a,
                                                   _Float16* __restrict__ xh,
                                                   _Float16* __restrict__ xl,
                                                   _Float16* __restrict__ sh,
                                                   _Float16* __restrict__ sl,
                                                   float* __restrict__ xn,
                                                   _Float16* __restrict__ ah,
                                                   _Float16* __restrict__ al,
                                                   float* __restrict__ svnp) {
    if (blockIdx.x >= ROW_BLOCKS) {
        int idx = (blockIdx.x - ROW_BLOCKS) * 256 + threadIdx.x;
        int r = idx / SPAD, col = idx - r * SPAD;
        int cls = col >> 9, j = col & 511;
        int s = cls * NV + ((j < NV) ? j : NV - 1);
        float av = (r < R && j < NV) ? a[(size_t)r * S + s] : 0.0f;
        _Float16 h = (_Float16)av;
        ah[idx] = h;
        al[idx] = (_Float16)((av - (float)h) * 4096.0f);
        return;
    }
    int gid  = blockIdx.x * blockDim.x + threadIdx.x;
    int wid  = gid >> 6;
    int lane = gid & 63;
    bool isx = wid < N;
    int  r   = isx ? wid : wid - N;
    const float* row = isx ? (x + (size_t)r * D) : (sv + (size_t)r * D);
    float4 v = reinterpret_cast<const float4*>(row)[lane];
    float s = v.x * v.x + v.y * v.y + v.z * v.z + v.w * v.w;
#pragma unroll
    for (int off = 32; off > 0; off >>= 1) s += __shfl_xor(s, off, 64);
    float vv[4] = {v.x, v.y, v.z, v.w};
    f16x4 h, l;
#pragma unroll
    for (int k = 0; k < 4; ++k) {
        _Float16 hi = (_Float16)vv[k];
        h[k] = hi;
        l[k] = (_Float16)((vv[k] - (float)hi) * 4096.0f);
    }
    size_t o = (size_t)r * D + lane * 4;
    *(f16x4*)((isx ? xh : sh) + o) = h;
    *(f16x4*)((isx ? xl : sl) + o) = l;
    if (lane == 0) {
        if (isx) {
            xn[r] = s;
        } else {
            int cls = r / NV, j = r - cls * NV;
            svnp[cls * 512 + j] = s;
            if (j == NV - 1)                      // fill pad cols 500..511
                for (int p = NV; p < 512; ++p) svnp[cls * 512 + p] = s;
        }
    }
}

// ---------------- swapped split-MFMA GEMM + exp + PV-MFMA reduce ------------
// grid: (128 row tiles, 10 classes). block 256 = 4 waves (wm,wn 2x2).
// wave tile: 64 sv x 32 n = 4x2 mfma tiles (16x16x32). 32 phases =
// 4 sv-chunks x 8 kb; gload_lds DMA double-buffer.
// Phase: {issue stage(ph+1); vmcnt(6); s_barrier; [chunk top: epilogue-
// const prefetch to regs]; ds_reads; setprio MFMAs; [ph==7: epilogue from
// regs]; lgkmcnt(0); s_barrier} -- prefetch never force-drained.
__global__ __launch_bounds__(256, 3) void svc_gemm(const _Float16* __restrict__ xh,
                                                   const _Float16* __restrict__ xl,
                                                   const _Float16* __restrict__ sh,
                                                   const _Float16* __restrict__ sl,
                                                   const _Float16* __restrict__ ahp,
                                                   const _Float16* __restrict__ alp,
                                                   const float* __restrict__ xnorm,
                                                   const float* __restrict__ svnp,
                                                   float* __restrict__ T) {
    __shared__ _Float16 SVs[2][2][128 * 32];  // 32KB: M-operand (sv rows)
    __shared__ _Float16 Xs[2][2][64 * 32];    // 16KB: N-operand (x rows)

    const int tid  = threadIdx.x;
    const int n0   = blockIdx.x * 64;
    const int cls  = blockIdx.y;
    const int w    = tid >> 6;
    const int lane = tid & 63;
    const int wm   = w >> 1;   // splits 128 m
    const int wn   = w & 1;    // splits 64 n
    const int lx   = lane & 15;
    const int quad = lane >> 4;

    float xnr[2];
#pragma unroll
    for (int nt = 0; nt < 2; ++nt)
        xnr[nt] = xnorm[n0 + wn * 32 + nt * 16 + lx];

    int svoff[4], xoff[2];
#pragma unroll
    for (int mt = 0; mt < 4; ++mt) {
        int row = wm * 64 + mt * 16 + lx;
        svoff[mt] = row * 32 + ((quad - (row >> 1)) & 3) * 8;
    }
#pragma unroll
    for (int nt = 0; nt < 2; ++nt) {
        int row = wn * 32 + nt * 16 + lx;
        xoff[nt] = row * 32 + ((quad - (row >> 1)) & 3) * 8;
    }

    const int arow = tid >> 2, ag = tid & 3;
    const int sg   = (ag + (arow >> 1)) & 3;
    const int segend = cls * NV + NV - 1;
    const int ldsw = w * 512;

    auto stage = [&](int ph, int buf) {
        const int ch = ph >> 3, kb = ph & 7;
        const size_t koff = (size_t)(kb * 32 + sg * 8);
        const size_t goX  = (size_t)(n0 + arow) * D + koff;
        gload16(xh + goX, &Xs[buf][0][ldsw]);
        gload16(xl + goX, &Xs[buf][1][ldsw]);
        const int svbase = cls * NV + ch * 128;
        int svr0 = svbase + arow;      if (svr0 > segend) svr0 = segend;
        int svr1 = svbase + arow + 64; if (svr1 > segend) svr1 = segend;
        const size_t go0 = (size_t)svr0 * D + koff;
        const size_t go1 = (size_t)svr1 * D + koff;
        gload16(sh + go0, &SVs[buf][0][ldsw]);
        gload16(sl + go0, &SVs[buf][1][ldsw]);
        gload16(sh + go1, &SVs[buf][0][2048 + ldsw]);
        gload16(sl + go1, &SVs[buf][1][2048 + ldsw]);
    };

    f32x4 accM[4][2], accC[4][2];      // first-GEMM tiles [mt][nt]
#pragma unroll
    for (int mt = 0; mt < 4; ++mt)
#pragma unroll
        for (int nt = 0; nt < 2; ++nt) {
            accM[mt][nt] = (f32x4){0.f, 0.f, 0.f, 0.f};
            accC[mt][nt] = (f32x4){0.f, 0.f, 0.f, 0.f};
        }
    f32x4 accO[2], accOC[2];           // PV output tiles [nt] (r x n)
#pragma unroll
    for (int nt = 0; nt < 2; ++nt) {
        accO[nt]  = (f32x4){0.f, 0.f, 0.f, 0.f};
        accOC[nt] = (f32x4){0.f, 0.f, 0.f, 0.f};
    }

    // epilogue constants for the CURRENT chunk, prefetched at chunk top
    f16x4 eh[4], el[4];
    float4 es[4];

    stage(0, 0);

    for (int ph = 0; ph < 32; ++ph) {
        const int buf = ph & 1;
        // phase top: issue next stage, counted drain of stage(ph) only
        if (ph < 31) {
            stage(ph + 1, buf ^ 1);
            asm volatile("s_waitcnt vmcnt(6)" ::: "memory");
        } else {
            asm volatile("s_waitcnt vmcnt(0)" ::: "memory");
        }
        __builtin_amdgcn_s_barrier();      // all waves' stage(ph) visible
        asm volatile("" ::: "memory");

        if ((ph & 7) == 0) {
            // chunk top: prefetch epilogue constants into registers. Issued
            // AFTER stage(ph+1): they are drained as a side effect of the
            // NEXT phases' vmcnt(6) (they're older than the newest 6) and
            // are register-resident by ph==7 -- consumption forces no drain.
            const int ch = ph >> 3;
            const int mbase = cls * 512 + ch * 128 + wm * 64;
#pragma unroll
            for (int mt = 0; mt < 4; ++mt) {
                const size_t ao = (size_t)lx * SPAD + mbase + mt * 16 + quad * 4;
                eh[mt] = *(const f16x4*)(ahp + ao);   // A-frag: a[r=lx, k]
                el[mt] = *(const f16x4*)(alp + ao);
                es[mt] = *(const float4*)(svnp + mbase + mt * 16 + quad * 4);
            }
        }

        f16x8 Am[2][4], Bx[2][2];
#pragma unroll
        for (int mt = 0; mt < 4; ++mt) {
            Am[0][mt] = *(const f16x8*)(&SVs[buf][0][svoff[mt]]);
            Am[1][mt] = *(const f16x8*)(&SVs[buf][1][svoff[mt]]);
        }
#pragma unroll
        for (int nt = 0; nt < 2; ++nt) {
            Bx[0][nt] = *(const f16x8*)(&Xs[buf][0][xoff[nt]]);
            Bx[1][nt] = *(const f16x8*)(&Xs[buf][1][xoff[nt]]);
        }
        __builtin_amdgcn_s_setprio(1);
#pragma unroll
        for (int mt = 0; mt < 4; ++mt)
#pragma unroll
            for (int nt = 0; nt < 2; ++nt) {
                accM[mt][nt] = __builtin_amdgcn_mfma_f32_16x16x32_f16(
                    Am[0][mt], Bx[0][nt], accM[mt][nt], 0, 0, 0);
                accC[mt][nt] = __builtin_amdgcn_mfma_f32_16x16x32_f16(
                    Am[0][mt], Bx[1][nt], accC[mt][nt], 0, 0, 0);
                accC[mt][nt] = __builtin_amdgcn_mfma_f32_16x16x32_f16(
                    Am[1][mt], Bx[0][nt], accC[mt][nt], 0, 0, 0);
            }
        __builtin_amdgcn_s_setprio(0);

        if ((ph & 7) == 7) {   // chunk done: exp + PV-MFMA reduce, all-reg
#pragma unroll
            for (int mt = 0; mt < 4; ++mt) {
#pragma unroll
                for (int nt = 0; nt < 2; ++nt) {
                    f16x4 bh, bl;   // B-frag: kv[k = quad*4+reg, col = lx]
#pragma unroll
                    for (int reg = 0; reg < 4; ++reg) {
                        float dot = accM[mt][nt][reg]
                                  + accC[mt][nt][reg] * (1.0f / 4096.0f);
                        float e  = fmaf(2.0f * GAMMA, dot,
                                        -GAMMA * (xnr[nt] + es[mt][reg]));
                        float kv = __expf(e);
                        _Float16 h = (_Float16)kv;
                        bh[reg] = h;
                        bl[reg] = (_Float16)((kv - (float)h) * 4096.0f);
                    }
                    accO[nt]  = __builtin_amdgcn_mfma_f32_16x16x16f16(
                        eh[mt], bh, accO[nt], 0, 0, 0);
                    accOC[nt] = __builtin_amdgcn_mfma_f32_16x16x16f16(
                        eh[mt], bl, accOC[nt], 0, 0, 0);
                    accOC[nt] = __builtin_amdgcn_mfma_f32_16x16x16f16(
                        el[mt], bh, accOC[nt], 0, 0, 0);
                    accM[mt][nt] = (f32x4){0.f, 0.f, 0.f, 0.f};
                    accC[mt][nt] = (f32x4){0.f, 0.f, 0.f, 0.f};
                }
            }
        }

        // phase bottom: ds_reads of buf done; barrier guards next DMA. NO vmcnt.
        asm volatile("s_waitcnt lgkmcnt(0)" ::: "memory");
        __builtin_amdgcn_s_barrier();
        asm volatile("" ::: "memory");
    }

    // cross-wm reduce via 8KB of reused SVs space, then store T ([90][N]).
    float* scr = (float*)&SVs[0][0][0];
    if (wm == 0) {
#pragma unroll
        for (int nt = 0; nt < 2; ++nt)
#pragma unroll
            for (int reg = 0; reg < 4; ++reg) {
                int base = ((wn * 2 + nt) * 2) * 256 + (quad * 4 + reg) * 16 + lx;
                scr[base]       = accO[nt][reg];
                scr[base + 256] = accOC[nt][reg];
            }
    }
    __syncthreads();
    if (wm == 1) {
#pragma unroll
        for (int nt = 0; nt < 2; ++nt)
#pragma unroll
            for (int reg = 0; reg < 4; ++reg) {
                int r = quad * 4 + reg;
                if (r < R) {
                    int base = ((wn * 2 + nt) * 2) * 256 + r * 16 + lx;
                    float o  = accO[nt][reg]  + scr[base];
                    float oc = accOC[nt][reg] + scr[base + 256];
                    int n = n0 + wn * 32 + nt * 16 + lx;
                    T[(size_t)(r * 10 + cls) * N + n] = o + oc * (1.0f / 4096.0f);
                }
            }
    }
}

// ---------------- pairwise voting + argmax ----------------------------------
// T is [90][N]: every load below is a coalesced 1KB/wave read.
__global__ __launch_bounds__(256) void vote_kernel(const float* __restrict__ T,
                                                   const float* __restrict__ b,
                                                   int* __restrict__ out) {
    int n = blockIdx.x * blockDim.x + threadIdx.x;
    if (n >= N) return;
    float tv[90];
#pragma unroll
    for (int i = 0; i < 90; ++i) tv[i] = T[(size_t)i * N + n];
    int counts[C];
#pragma unroll
    for (int k = 0; k < C; ++k) counts[k] = 0;
    int p = 0;
#pragma unroll
    for (int i = 0; i < C; ++i) {
#pragma unroll
        for (int j = i + 1; j < C; ++j) {
            float c = tv[i * 10 + j] + tv[(j - 1) * 10 + i] + b[p];
            if (c > 0.f) counts[i]++; else counts[j]++;
            ++p;
        }
    }
    int best = 0;
#pragma unroll
    for (int k = 1; k < C; ++k)
        if (counts[k] > counts[best]) best = k;
    out[n]     = best;
    out[N + n] = best;
}

extern "C" void kernel_launch(void* const* d_in, const int* in_sizes, int n_in,
                              void* d_out, int out_size, void* d_ws, size_t ws_size,
                              hipStream_t stream) {
    const float* x  = (const float*)d_in[0];   // [8192,256]
    const float* sv = (const float*)d_in[1];   // [5000,256]
    const float* a  = (const float*)d_in[2];   // [9,5000]
    const float* b  = (const float*)d_in[3];   // [45]
    int* out = (int*)d_out;

    char* wp = (char*)d_ws;
    _Float16* xh = (_Float16*)wp;  wp += (size_t)N * D * 2;
    _Float16* xl = (_Float16*)wp;  wp += (size_t)N * D * 2;
    _Float16* sh = (_Float16*)wp;  wp += (size_t)S * D * 2;
    _Float16* sl = (_Float16*)wp;  wp += (size_t)S * D * 2;
    float* xnorm  = (float*)wp;    wp += (size_t)N * 4;
    _Float16* ahp = (_Float16*)wp; wp += (size_t)16 * SPAD * 2;
    _Float16* alp = (_Float16*)wp; wp += (size_t)16 * SPAD * 2;
    float* svnp   = (float*)wp;    wp += (size_t)SPAD * 4;
    float* T      = (float*)wp;    // [90][N]

    {   // fused split + norms + a-split + svnp (one launch)
        prep_kernel<<<ROW_BLOCKS + A_BLOCKS, 256, 0, stream>>>(
            x, sv, a, xh, xl, sh, sl, xnorm, ahp, alp, svnp);
    }
    {   // swapped GEMM + PV-MFMA reduce
        dim3 grid(N / 64, C);
        svc_gemm<<<grid, 256, 0, stream>>>(xh, xl, sh, sl, ahp, alp,
                                           xnorm, svnp, T);
    }
    {   // voting
        vote_kernel<<<N / 256, 256, 0, stream>>>(T, b, out);
    }
}

// Round 12
// 165.668 us; speedup vs baseline: 1.2116x; 1.0475x over previous
//
#include <hip/hip_runtime.h>
#include <hip/hip_fp16.h>
#include <cmath>

// SVC_63737314673237 round 14: R12's "X off the DS pipe" done correctly.
// R13 post-mortem: +32 epilogue-prefetch regs blew the (256,3) unified-reg
// cap -> scratch spill (WRITE 2.9->49.5MB) -> revert epilogue to R10 inline.
// R12 post-mortem: direct X frag loads were lane-stride-512B gathers.
// R14 fix: prep stores X TRANSPOSED, fragment-major: Xt[pn][kb][quad][lx][8]
// -> lane fragment at ((pn*8+kb)*4+quad)*128 + lx*8 f16 = consecutive-lx
// 16B = fully coalesced 1KB/wave dwordx4, L2-resident. X never touches
// LDS/DS: ds_reads 12->8 per wave-phase, DMA 6->4 loads, LDS 48->32KB.
// Schedule = R12's proven unroll-2 + vmcnt(8) counted drain (VGPR 84, fits
// (256,3)). SV path/hash/epilogue/T-layout verbatim R10 (session best).

#define GAMMA 0.01f
constexpr int N  = 8192;
constexpr int D  = 256;
constexpr int S  = 5000;
constexpr int C  = 10;
constexpr int NV = 500;
constexpr int R  = 9;     // C-1
constexpr int SPAD = 5120; // 10 classes x 512 padded cols

constexpr int ROW_BLOCKS = (N + S) / 4;       // 3298 (13192 row-waves, 4/block)
constexpr int A_BLOCKS   = (16 * SPAD) / 256; // 320

typedef _Float16 f16x8 __attribute__((ext_vector_type(8)));
typedef _Float16 f16x4 __attribute__((ext_vector_type(4)));
typedef float    f32x4 __attribute__((ext_vector_type(4)));

__device__ __forceinline__ void gload16(const void* g, void* l) {
    __builtin_amdgcn_global_load_lds(
        (const __attribute__((address_space(1))) void*)g,
        (__attribute__((address_space(3))) void*)l, 16, 0, 0);
}

// ---------------- fused split + norms + a-split + svnp ----------------------
// x rows are stored TRANSPOSED fragment-major: granule (pn,kb,quad,lx)
// holds x[pn*16+lx][kb*32+quad*8 .. +8). sv rows stay row-major (LDS path).
__global__ __launch_bounds__(256) void prep_kernel(const float* __restrict__ x,
                                                   const float* __restrict__ sv,
                                                   const float* __restrict__ a,
                                                   _Float16* __restrict__ xth,
                                                   _Float16* __restrict__ xtl,
                                                   _Float16* __restrict__ sh,
                                                   _Float16* __restrict__ sl,
                                                   float* __restrict__ xn,
                                                   _Float16* __restrict__ ah,
                                                   _Float16* __restrict__ al,
                                                   float* __restrict__ svnp) {
    if (blockIdx.x >= ROW_BLOCKS) {
        int idx = (blockIdx.x - ROW_BLOCKS) * 256 + threadIdx.x;
        int r = idx / SPAD, col = idx - r * SPAD;
        int cls = col >> 9, j = col & 511;
        int s = cls * NV + ((j < NV) ? j : NV - 1);
        float av = (r < R && j < NV) ? a[(size_t)r * S + s] : 0.0f;
        _Float16 h = (_Float16)av;
        ah[idx] = h;
        al[idx] = (_Float16)((av - (float)h) * 4096.0f);
        return;
    }
    int gid  = blockIdx.x * blockDim.x + threadIdx.x;
    int wid  = gid >> 6;
    int lane = gid & 63;
    bool isx = wid < N;
    int  r   = isx ? wid : wid - N;
    const float* row = isx ? (x + (size_t)r * D) : (sv + (size_t)r * D);
    float4 v = reinterpret_cast<const float4*>(row)[lane];
    float s = v.x * v.x + v.y * v.y + v.z * v.z + v.w * v.w;
#pragma unroll
    for (int off = 32; off > 0; off >>= 1) s += __shfl_xor(s, off, 64);
    float vv[4] = {v.x, v.y, v.z, v.w};
    f16x4 h, l;
#pragma unroll
    for (int k = 0; k < 4; ++k) {
        _Float16 hi = (_Float16)vv[k];
        h[k] = hi;
        l[k] = (_Float16)((vv[k] - (float)hi) * 4096.0f);
    }
    if (isx) {
        // lane covers k = 4*lane..4*lane+3: kb = lane>>3, quad = (lane>>1)&3,
        // elem = (lane&1)*4. Granule base + lx*8.
        size_t xt = (((size_t)(r >> 4) * 8 + (lane >> 3)) * 4 + ((lane >> 1) & 3)) * 128
                  + (size_t)(r & 15) * 8 + (lane & 1) * 4;
        *(f16x4*)(xth + xt) = h;
        *(f16x4*)(xtl + xt) = l;
    } else {
        size_t o = (size_t)r * D + lane * 4;
        *(f16x4*)(sh + o) = h;
        *(f16x4*)(sl + o) = l;
    }
    if (lane == 0) {
        if (isx) {
            xn[r] = s;
        } else {
            int cls = r / NV, j = r - cls * NV;
            svnp[cls * 512 + j] = s;
            if (j == NV - 1)                      // fill pad cols 500..511
                for (int p = NV; p < 512; ++p) svnp[cls * 512 + p] = s;
        }
    }
}

// ---------------- swapped split-MFMA GEMM + exp + PV-MFMA reduce ------------
// grid: (128 row tiles, 10 classes). block 256 = 4 waves (wm,wn 2x2).
// wave tile: 64 sv x 32 n = 4x2 mfma tiles (16x16x32). 32 phases =
// 4 sv-chunks x 8 kb. SV via gload_lds double-buffer (32KB, conflict-free
// (row>>1)&3 hash); X via double-buffered REGISTER frags from transposed
// layout (coalesced 16B/lane). Unroll-2 phases; counted vmcnt(8).
__global__ __launch_bounds__(256, 3) void svc_gemm(const _Float16* __restrict__ xth,
                                                   const _Float16* __restrict__ xtl,
                                                   const _Float16* __restrict__ sh,
                                                   const _Float16* __restrict__ sl,
                                                   const _Float16* __restrict__ ahp,
                                                   const _Float16* __restrict__ alp,
                                                   const float* __restrict__ xnorm,
                                                   const float* __restrict__ svnp,
                                                   float* __restrict__ T) {
    __shared__ _Float16 SVs[2][2][128 * 32];  // 32KB: M-operand (sv rows)

    const int tid  = threadIdx.x;
    const int n0   = blockIdx.x * 64;
    const int cls  = blockIdx.y;
    const int w    = tid >> 6;
    const int lane = tid & 63;
    const int wm   = w >> 1;   // splits 128 m
    const int wn   = w & 1;    // splits 64 n
    const int lx   = lane & 15;
    const int quad = lane >> 4;

    float xnr[2];
#pragma unroll
    for (int nt = 0; nt < 2; ++nt)
        xnr[nt] = xnorm[n0 + wn * 32 + nt * 16 + lx];

    // Am fragment read offsets, inverse of staged K-slot perm (row>>1)&3
    int svoff[4];
#pragma unroll
    for (int mt = 0; mt < 4; ++mt) {
        int row = wm * 64 + mt * 16 + lx;
        svoff[mt] = row * 32 + ((quad - (row >> 1)) & 3) * 8;
    }

    const int arow = tid >> 2, ag = tid & 3;
    const int sg   = (ag + (arow >> 1)) & 3;
    const int segend = cls * NV + NV - 1;
    const int ldsw = w * 512;

    auto stage = [&](int ph, int buf) {
        const int ch = ph >> 3, kb = ph & 7;
        const size_t koff = (size_t)(kb * 32 + sg * 8);
        const int svbase = cls * NV + ch * 128;
        int svr0 = svbase + arow;      if (svr0 > segend) svr0 = segend;
        int svr1 = svbase + arow + 64; if (svr1 > segend) svr1 = segend;
        const size_t go0 = (size_t)svr0 * D + koff;
        const size_t go1 = (size_t)svr1 * D + koff;
        gload16(sh + go0, &SVs[buf][0][ldsw]);
        gload16(sl + go0, &SVs[buf][1][ldsw]);
        gload16(sh + go1, &SVs[buf][0][2048 + ldsw]);
        gload16(sl + go1, &SVs[buf][1][2048 + ldsw]);
    };

    // transposed-X fragment bases for this lane: panel pn = n>>4
    const int pn0 = blockIdx.x * 4 + wn * 2;       // nt=0 panel
    const size_t xq = (size_t)quad * 128 + (size_t)lx * 8;
    f16x8 pBE[2][2], pBO[2][2];        // [plane][nt], double-buffered
    auto loadB = [&](f16x8 (&dst)[2][2], int kb) {
        const size_t o0 = ((size_t)(pn0 * 8 + kb) * 4) * 128 + xq;
        const size_t o1 = ((size_t)((pn0 + 1) * 8 + kb) * 4) * 128 + xq;
        dst[0][0] = *(const f16x8*)(xth + o0);
        dst[1][0] = *(const f16x8*)(xtl + o0);
        dst[0][1] = *(const f16x8*)(xth + o1);
        dst[1][1] = *(const f16x8*)(xtl + o1);
    };

    f32x4 accM[4][2], accC[4][2];      // first-GEMM tiles [mt][nt]
#pragma unroll
    for (int mt = 0; mt < 4; ++mt)
#pragma unroll
        for (int nt = 0; nt < 2; ++nt) {
            accM[mt][nt] = (f32x4){0.f, 0.f, 0.f, 0.f};
            accC[mt][nt] = (f32x4){0.f, 0.f, 0.f, 0.f};
        }
    f32x4 accO[2], accOC[2];           // PV output tiles [nt] (r x n)
#pragma unroll
    for (int nt = 0; nt < 2; ++nt) {
        accO[nt]  = (f32x4){0.f, 0.f, 0.f, 0.f};
        accOC[nt] = (f32x4){0.f, 0.f, 0.f, 0.f};
    }

    auto compute = [&](int buf, const f16x8 (&pB)[2][2]) {
        f16x8 Am[2][4];
#pragma unroll
        for (int mt = 0; mt < 4; ++mt) {
            Am[0][mt] = *(const f16x8*)(&SVs[buf][0][svoff[mt]]);
            Am[1][mt] = *(const f16x8*)(&SVs[buf][1][svoff[mt]]);
        }
        __builtin_amdgcn_s_setprio(1);
#pragma unroll
        for (int mt = 0; mt < 4; ++mt)
#pragma unroll
            for (int nt = 0; nt < 2; ++nt) {
                accM[mt][nt] = __builtin_amdgcn_mfma_f32_16x16x32_f16(
                    Am[0][mt], pB[0][nt], accM[mt][nt], 0, 0, 0);
                accC[mt][nt] = __builtin_amdgcn_mfma_f32_16x16x32_f16(
                    Am[0][mt], pB[1][nt], accC[mt][nt], 0, 0, 0);
                accC[mt][nt] = __builtin_amdgcn_mfma_f32_16x16x32_f16(
                    Am[1][mt], pB[0][nt], accC[mt][nt], 0, 0, 0);
            }
        __builtin_amdgcn_s_setprio(0);
    };

    auto epilogue = [&](int ch) {       // exp + PV-MFMA reduce (R10 inline)
        const int mbase = cls * 512 + ch * 128 + wm * 64;
#pragma unroll
        for (int mt = 0; mt < 4; ++mt) {
            const size_t ao = (size_t)lx * SPAD + mbase + mt * 16 + quad * 4;
            f16x4 afh = *(const f16x4*)(ahp + ao);   // A-frag: a[r=lx, k]
            f16x4 afl = *(const f16x4*)(alp + ao);
            float4 sn4 = *(const float4*)(svnp + mbase + mt * 16 + quad * 4);
#pragma unroll
            for (int nt = 0; nt < 2; ++nt) {
                f16x4 bh, bl;   // B-frag: kv[k = quad*4+reg, col = lx]
#pragma unroll
                for (int reg = 0; reg < 4; ++reg) {
                    float dot = accM[mt][nt][reg]
                              + accC[mt][nt][reg] * (1.0f / 4096.0f);
                    float e  = fmaf(2.0f * GAMMA, dot,
                                    -GAMMA * (xnr[nt] + sn4[reg]));
                    float kv = __expf(e);
                    _Float16 h = (_Float16)kv;
                    bh[reg] = h;
                    bl[reg] = (_Float16)((kv - (float)h) * 4096.0f);
                }
                accO[nt]  = __builtin_amdgcn_mfma_f32_16x16x16f16(
                    afh, bh, accO[nt], 0, 0, 0);
                accOC[nt] = __builtin_amdgcn_mfma_f32_16x16x16f16(
                    afh, bl, accOC[nt], 0, 0, 0);
                accOC[nt] = __builtin_amdgcn_mfma_f32_16x16x16f16(
                    afl, bh, accOC[nt], 0, 0, 0);
                accM[mt][nt] = (f32x4){0.f, 0.f, 0.f, 0.f};
                accC[mt][nt] = (f32x4){0.f, 0.f, 0.f, 0.f};
            }
        }
    };

    stage(0, 0);
    loadB(pBE, 0);

    for (int it = 0; it < 16; ++it) {
        const int ph = it * 2;
        // ---- even phase (buf 0, frags pBE) ----
        stage(ph + 1, 1);
        loadB(pBO, (ph + 1) & 7);
        asm volatile("s_waitcnt vmcnt(8)" ::: "memory");   // stage(ph)+loadB(ph) done
        __builtin_amdgcn_s_barrier();
        asm volatile("" ::: "memory");
        compute(0, pBE);
        asm volatile("s_waitcnt lgkmcnt(0)" ::: "memory");
        __builtin_amdgcn_s_barrier();
        asm volatile("" ::: "memory");
        // ---- odd phase (buf 1, frags pBO) ----
        if (it < 15) {
            stage(ph + 2, 0);
            loadB(pBE, (ph + 2) & 7);
            asm volatile("s_waitcnt vmcnt(8)" ::: "memory");
        } else {
            asm volatile("s_waitcnt vmcnt(0)" ::: "memory");
        }
        __builtin_amdgcn_s_barrier();
        asm volatile("" ::: "memory");
        compute(1, pBO);
        if ((it & 3) == 3) epilogue(it >> 2);   // ph+1 == 7 mod 8
        asm volatile("s_waitcnt lgkmcnt(0)" ::: "memory");
        __builtin_amdgcn_s_barrier();
        asm volatile("" ::: "memory");
    }

    // cross-wm reduce via 8KB of reused SVs space, then store T ([90][N]).
    float* scr = (float*)&SVs[0][0][0];
    if (wm == 0) {
#pragma unroll
        for (int nt = 0; nt < 2; ++nt)
#pragma unroll
            for (int reg = 0; reg < 4; ++reg) {
                int base = ((wn * 2 + nt) * 2) * 256 + (quad * 4 + reg) * 16 + lx;
                scr[base]       = accO[nt][reg];
                scr[base + 256] = accOC[nt][reg];
            }
    }
    __syncthreads();
    if (wm == 1) {
#pragma unroll
        for (int nt = 0; nt < 2; ++nt)
#pragma unroll
            for (int reg = 0; reg < 4; ++reg) {
                int r = quad * 4 + reg;
                if (r < R) {
                    int base = ((wn * 2 + nt) * 2) * 256 + r * 16 + lx;
                    float o  = accO[nt][reg]  + scr[base];
                    float oc = accOC[nt][reg] + scr[base + 256];
                    int n = n0 + wn * 32 + nt * 16 + lx;
                    T[(size_t)(r * 10 + cls) * N + n] = o + oc * (1.0f / 4096.0f);
                }
            }
    }
}

// ---------------- pairwise voting + argmax ----------------------------------
// T is [90][N]: every load below is a coalesced 1KB/wave read.
__global__ __launch_bounds__(256) void vote_kernel(const float* __restrict__ T,
                                                   const float* __restrict__ b,
                                                   int* __restrict__ out) {
    int n = blockIdx.x * blockDim.x + threadIdx.x;
    if (n >= N) return;
    float tv[90];
#pragma unroll
    for (int i = 0; i < 90; ++i) tv[i] = T[(size_t)i * N + n];
    int counts[C];
#pragma unroll
    for (int k = 0; k < C; ++k) counts[k] = 0;
    int p = 0;
#pragma unroll
    for (int i = 0; i < C; ++i) {
#pragma unroll
        for (int j = i + 1; j < C; ++j) {
            float c = tv[i * 10 + j] + tv[(j - 1) * 10 + i] + b[p];
            if (c > 0.f) counts[i]++; else counts[j]++;
            ++p;
        }
    }
    int best = 0;
#pragma unroll
    for (int k = 1; k < C; ++k)
        if (counts[k] > counts[best]) best = k;
    out[n]     = best;
    out[N + n] = best;
}

extern "C" void kernel_launch(void* const* d_in, const int* in_sizes, int n_in,
                              void* d_out, int out_size, void* d_ws, size_t ws_size,
                              hipStream_t stream) {
    const float* x  = (const float*)d_in[0];   // [8192,256]
    const float* sv = (const float*)d_in[1];   // [5000,256]
    const float* a  = (const float*)d_in[2];   // [9,5000]
    const float* b  = (const float*)d_in[3];   // [45]
    int* out = (int*)d_out;

    char* wp = (char*)d_ws;
    _Float16* xth = (_Float16*)wp; wp += (size_t)N * D * 2;   // transposed X hi
    _Float16* xtl = (_Float16*)wp; wp += (size_t)N * D * 2;   // transposed X lo
    _Float16* sh  = (_Float16*)wp; wp += (size_t)S * D * 2;
    _Float16* sl  = (_Float16*)wp; wp += (size_t)S * D * 2;
    float* xnorm  = (float*)wp;    wp += (size_t)N * 4;
    _Float16* ahp = (_Float16*)wp; wp += (size_t)16 * SPAD * 2;
    _Float16* alp = (_Float16*)wp; wp += (size_t)16 * SPAD * 2;
    float* svnp   = (float*)wp;    wp += (size_t)SPAD * 4;
    float* T      = (float*)wp;    // [90][N]

    {   // fused split + norms + a-split + svnp (one launch)
        prep_kernel<<<ROW_BLOCKS + A_BLOCKS, 256, 0, stream>>>(
            x, sv, a, xth, xtl, sh, sl, xnorm, ahp, alp, svnp);
    }
    {   // swapped GEMM + PV-MFMA reduce
        dim3 grid(N / 64, C);
        svc_gemm<<<grid, 256, 0, stream>>>(xth, xtl, sh, sl, ahp, alp,
                                           xnorm, svnp, T);
    }
    {   // voting
        vote_kernel<<<N / 256, 256, 0, stream>>>(T, b, out);
    }
}